// Round 9
// baseline (105.422 us; speedup 1.0000x reference)
//
#include <hip/hip_runtime.h>
#include <hip/hip_bf16.h>
#include <stdint.h>

// Problem constants
#define KD 2304    // K = C*3*3
#define LD 3136    // L = 56*56
#define ND 256     // output channels
#define MD 25088   // B*L
#define CD 256     // input channels
#define PITCH 64   // padded row pitch (floats)
#define PROWS 58
#define PLANE (PROWS * PITCH)

typedef __bf16 bf16x8 __attribute__((ext_vector_type(8)));
typedef float f32x4 __attribute__((ext_vector_type(4)));
typedef float f32x4u __attribute__((ext_vector_type(4), aligned(4)));

__device__ __forceinline__ void gload_lds16(const void* g, void* l) {
  __builtin_amdgcn_global_load_lds(
      (const __attribute__((address_space(1))) unsigned int*)g,
      (__attribute__((address_space(3))) unsigned int*)l, 16, 0, 0);
}

// ---------------- Phase -1: zero-pad x into [B*C][58][PITCH=64] ----------------
__global__ __launch_bounds__(256) void pad_kernel(
    const float* __restrict__ x, float* __restrict__ xpad) {
  const int plane = blockIdx.x;
  const float* src = x + (size_t)plane * LD;
  float* dst = xpad + (size_t)plane * PLANE;
  const int cc4 = (threadIdx.x & 15) * 4;
  const int r0 = threadIdx.x >> 4;
#pragma unroll
  for (int p = 0; p < 4; ++p) {
    const int r = r0 + p * 16;
    if (r >= PROWS) continue;
    f32x4 o = {0.f, 0.f, 0.f, 0.f};
    if (r >= 1 && r <= 56) {
      const float* srow = src + (r - 1) * 56;
      if (cc4 == 0) {
        f32x4u v = *(const f32x4u*)(srow);
        o[1] = v[0]; o[2] = v[1]; o[3] = v[2];
      } else if (cc4 <= 52) {
        o = *(const f32x4u*)(srow + cc4 - 1);
      } else if (cc4 == 56) {
        f32x4u v = *(const f32x4u*)(srow + 52);
        o[0] = v[3];
      }
    }
    *(f32x4*)(dst + r * PITCH + cc4) = o;
  }
}

// ---------------- Phase 0: weight fake-quant -> wqT [N][K] bf16 ----------------
__global__ __launch_bounds__(256) void quant_w_kernel(
    const float* __restrict__ w, __hip_bfloat16* __restrict__ wqT) {
  const int gk = blockIdx.x % 72;
  const int gn = blockIdx.x / 72;
  const int n = gn * 32 + (threadIdx.x >> 3);
  const int k = gk * 32 + (threadIdx.x & 7) * 4;
  const float4 v = *(const float4*)(w + (size_t)n * KD + k);
  float a = fmaxf(fmaxf(fabsf(v.x), fabsf(v.y)), fmaxf(fabsf(v.z), fabsf(v.w)));
#pragma unroll
  for (int m = 1; m <= 32; m <<= 1) a = fmaxf(a, __shfl_xor(a, m, 64));
  __shared__ float red[4];
  if ((threadIdx.x & 63) == 0) red[threadIdx.x >> 6] = a;
  __syncthreads();
  const float mx = fmaxf(fmaxf(red[0], red[1]), fmaxf(red[2], red[3]));
  const float r63 = (mx == 0.f) ? 0.f : 63.f / mx;
  const float scale = mx * (1.f / 63.f);
  ushort4 o;
  o.x = __builtin_bit_cast(unsigned short, __float2bfloat16(rintf(v.x * r63) * scale));
  o.y = __builtin_bit_cast(unsigned short, __float2bfloat16(rintf(v.y * r63) * scale));
  o.z = __builtin_bit_cast(unsigned short, __float2bfloat16(rintf(v.z * r63) * scale));
  o.w = __builtin_bit_cast(unsigned short, __float2bfloat16(rintf(v.w * r63) * scale));
  *(ushort4*)((unsigned short*)wqT + (size_t)n * KD + k) = o;
}

// ---- phase-exact window load for one 32-k granule (minimal register count) ----
template <int KP0>
__device__ __forceinline__ void qloadT(const float* __restrict__ pb, int p0, int c0,
                                       f32x4u (&win)[5][3]) {
  constexpr int NCH = (KP0 + 31) / 9 + 1;   // 4 or 5 channels
#pragma unroll
  for (int dc = 0; dc < 5; ++dc) {
    if (dc >= NCH) continue;
    const int tlo = (dc == 0) ? KP0 : 0;
    const int thi = (dc == NCH - 1) ? (KP0 + 31 - 9 * (NCH - 1)) : 8;
    const int cdc = (c0 + dc > 255) ? 255 : c0 + dc;   // clamp for tail dummies
    const float* cp = pb + p0 + cdc * PLANE;
#pragma unroll
    for (int di = 0; di < 3; ++di) {
      if (di >= tlo / 3 && di <= thi / 3)
        win[dc][di] = *(const f32x4u*)(cp + di * PITCH);
    }
  }
}

// ---- finish quant: extract, tree-max, rcp, quant, cvt_pk, swizzled As write ----
// As rows are 128B (64 k); 8 units of 16B; unit u of row r holds logical u^(r&7).
template <int KP0>
__device__ __forceinline__ void qfinishT(const f32x4u (&win)[5][3],
                                         char* __restrict__ as_base,
                                         int lane, unsigned cbase) {
  float v[32];
#pragma unroll
  for (int t = 0; t < 32; ++t) {
    const int idx = KP0 + t;
    v[t] = win[idx / 9][(idx % 9) / 3][(idx % 9) % 3];
  }
  float m16[16];
#pragma unroll
  for (int t = 0; t < 16; ++t)
    m16[t] = fmaxf(__builtin_fabsf(v[2 * t]), __builtin_fabsf(v[2 * t + 1]));
#pragma unroll
  for (int t = 0; t < 8; ++t) m16[t] = fmaxf(m16[t], m16[t + 8]);
#pragma unroll
  for (int t = 0; t < 4; ++t) m16[t] = fmaxf(m16[t], m16[t + 4]);
  const float mx = fmaxf(fmaxf(m16[0], m16[1]), fmaxf(m16[2], m16[3]));
  float r63 = 63.f * __builtin_amdgcn_rcpf(mx);
  r63 = (mx == 0.f) ? 0.f : r63;
  const float scale = mx * (1.f / 63.f);
  unsigned pk[16];
#pragma unroll
  for (int t = 0; t < 16; ++t) {
    const float a = rintf(v[2 * t] * r63) * scale;
    const float b = rintf(v[2 * t + 1] * r63) * scale;
    unsigned d;
    asm("v_cvt_pk_bf16_f32 %0, %1, %2" : "=v"(d) : "v"(a), "v"(b));
    pk[t] = d;
  }
  char* row = as_base + lane * 128;
  const unsigned swz = (unsigned)((lane & 7) << 4);
#pragma unroll
  for (int s = 0; s < 4; ++s) {
    uint4 o = {pk[4 * s], pk[4 * s + 1], pk[4 * s + 2], pk[4 * s + 3]};
    *(uint4*)(row + ((cbase + (unsigned)(s * 16)) ^ swz)) = o;
  }
}

#define SW_FIN(PH, DST, CB)                                                   \
  switch (PH) {                                                               \
    case 0: qfinishT<0>(win, DST, lane, CB); break;                           \
    case 1: qfinishT<1>(win, DST, lane, CB); break;                           \
    case 2: qfinishT<2>(win, DST, lane, CB); break;                           \
    case 3: qfinishT<3>(win, DST, lane, CB); break;                           \
    case 4: qfinishT<4>(win, DST, lane, CB); break;                           \
    case 5: qfinishT<5>(win, DST, lane, CB); break;                           \
    case 6: qfinishT<6>(win, DST, lane, CB); break;                           \
    case 7: qfinishT<7>(win, DST, lane, CB); break;                           \
    default: qfinishT<8>(win, DST, lane, CB); break;                          \
  }

#define SW_LOAD(PH, C0)                                                       \
  switch (PH) {                                                               \
    case 0: qloadT<0>(pb, p0, C0, win); break;                                \
    case 1: qloadT<1>(pb, p0, C0, win); break;                                \
    case 2: qloadT<2>(pb, p0, C0, win); break;                                \
    case 3: qloadT<3>(pb, p0, C0, win); break;                                \
    case 4: qloadT<4>(pb, p0, C0, win); break;                                \
    case 5: qloadT<5>(pb, p0, C0, win); break;                                \
    case 6: qloadT<6>(pb, p0, C0, win); break;                                \
    case 7: qloadT<7>(pb, p0, C0, win); break;                                \
    default: qloadT<8>(pb, p0, C0, win); break;                               \
  }

// ---- stage 256x64 wqT tile (32KB) via global_load_lds, pre-swizzled source ----
__device__ __forceinline__ void stage_ns(const unsigned short* __restrict__ wsrc,
                                         int k0, int lane, int w,
                                         char* __restrict__ Ns) {
#pragma unroll
  for (int sg = 0; sg < 4; ++sg) {
    const int c = w * 4 + sg;              // 0..31, 1KB chunk = 8 rows x 128B
    const int row = c * 8 + (lane >> 3);
    const int u = (lane & 7) ^ (row & 7);
    gload_lds16(wsrc + (size_t)row * KD + k0 + u * 8, Ns + c * 1024 + lane * 16);
  }
}

// ---- MFMA: 8 waves, wave tile 64n x 32m, BK=64 (2 k-slices) ----
__device__ __forceinline__ void mfma_phase(const char* __restrict__ AsC,
                                           const char* __restrict__ Ns,
                                           f32x4 (&acc)[4][2], int w, int lq, int hv) {
  const int wn = w & 3, wm = w >> 2;
#pragma unroll
  for (int kk = 0; kk < 2; ++kk) {
    bf16x8 af[4], bf[2];
#pragma unroll
    for (int i = 0; i < 4; ++i) {
      const unsigned rn = (unsigned)(wn * 64 + i * 16 + lq);
      const unsigned u = (unsigned)((kk * 4 + hv) ^ (rn & 7));
      af[i] = *(const bf16x8*)(Ns + rn * 128u + u * 16u);
    }
#pragma unroll
    for (int j = 0; j < 2; ++j) {
      const unsigned rm = (unsigned)(wm * 32 + j * 16 + lq);
      const unsigned u = (unsigned)((kk * 4 + hv) ^ (rm & 7));
      bf[j] = *(const bf16x8*)(AsC + rm * 128u + u * 16u);
    }
#pragma unroll
    for (int i = 0; i < 4; ++i)
#pragma unroll
      for (int j = 0; j < 2; ++j)
        acc[i][j] = __builtin_amdgcn_mfma_f32_16x16x32_bf16(
            af[i], bf[j], acc[i][j], 0, 0, 0);
  }
}

// ---------------- Fused: unfold+quant-A + B-stage + GEMM + bias ----------------
// 512 thr (8 waves), BM=64, BN=256 (quant-once, L2-minimal grid 392), BK=64,
// 36 iters. LDS = Ns 32K (single) + As 8K x ring-3 = 56KB -> 2 blocks/CU; VGPR
// capped 128 -> 16 waves/CU. Quant quarter-cadence: wave (slot=w&1, g=w>>1)
// quantizes on iters R==g (mod 4), producing As[(R+2)%3]; win prefetch issued
// post-MFMA (crosses lgkm-only bar2, 4-iter slack).
__global__ __launch_bounds__(512, 4) void fused_gemm_kernel(
    const float* __restrict__ xpad, const __hip_bfloat16* __restrict__ wqT,
    const float* __restrict__ bias, float* __restrict__ out) {
  __shared__ char smem[56 * 1024];
  char* As = smem;              // 3 x 8KB ring
  char* Ns = smem + 24576;      // 32KB
  const int tid = threadIdx.x;
  const int lane = tid & 63;
  const int w = __builtin_amdgcn_readfirstlane(tid >> 6);   // 0..7

  const int bid = blockIdx.x;                    // 0..391
  const int mt = (bid & 7) * 49 + (bid >> 3);    // XCD swizzle: image d -> XCD d
  const int m0 = mt * 64;

  const int b = m0 / LD;                         // uniform (3136 % 64 == 0)
  const int l = m0 - b * LD + lane;
  const int i = l / 56;
  const int j = l - i * 56;
  const float* pb = xpad + (size_t)b * CD * PLANE;
  const int p0 = i * PITCH + j;
  const unsigned short* wsrc = (const unsigned short*)wqT;

  const int slot = w & 1;                        // k-granule slot within BK=64
  const int g = w >> 1;                          // quant cadence group 0..3
  const unsigned cb = (unsigned)(slot * 64);     // byte base within 128B As row
  const int lq = lane & 15, hv = lane >> 4;

  f32x4 acc[4][2] = {};
  f32x4u win[5][3];

  // ---- prologue: groups 0,1 pre-fill As[0], As[1]; all prime win pipeline ----
  if (g < 2) {
    const int kp = 64 * g + 32 * slot;
    const int php = kp % 9;
    SW_LOAD(php, kp / 9);
    char* dst = As + g * 8192;
    SW_FIN(php, dst, cb);
  }
  int kq = 64 * (g + 2) + 32 * slot;             // next-consumed granule k
  int phq = kq % 9;
  {
    const int c0 = kq / 9;
    SW_LOAD(phq, c0);
  }
  asm volatile("s_waitcnt lgkmcnt(0)\n\ts_barrier" ::: "memory");
  __builtin_amdgcn_sched_barrier(0);

  for (int R = 0; R < 36; ++R) {
    stage_ns(wsrc, R * 64, lane, w, Ns);         // 4 async gload_lds -> Ns

    const bool qi = ((R & 3) == g);
    if (qi && R + 2 <= 35) {                     // produce As for iter R+2
      char* dst = As + ((R + 2) % 3) * 8192;
      SW_FIN(phq, dst, cb);
    }

    asm volatile("s_waitcnt vmcnt(0) lgkmcnt(0)\n\ts_barrier" ::: "memory");
    __builtin_amdgcn_sched_barrier(0);

    __builtin_amdgcn_s_setprio(1);
    mfma_phase(As + (R % 3) * 8192, Ns, acc, w, lq, hv);
    __builtin_amdgcn_s_setprio(0);

    if (qi && R + 6 <= 35) {                     // prefetch granule for iter R+6
      kq += 256;
      phq += 4; if (phq >= 9) phq -= 9;
      const int c0 = kq / 9;
      SW_LOAD(phq, c0);
    }

    asm volatile("s_waitcnt lgkmcnt(0)\n\ts_barrier" ::: "memory");  // no vmcnt!
    __builtin_amdgcn_sched_barrier(0);
  }

  // ---- Epilogue: D row = n = (w&3)*64 + i*16 + hv*4 + comp, col = m ----
#pragma unroll
  for (int i4 = 0; i4 < 4; ++i4) {
    const int nb = (w & 3) * 64 + i4 * 16 + hv * 4;
    const float4 b4 = *(const float4*)&bias[nb];
#pragma unroll
    for (int j2 = 0; j2 < 2; ++j2) {
      const int m = m0 + (w >> 2) * 32 + j2 * 16 + lq;
      const int ll = m - b * LD;
      float* op = out + ((size_t)b * ND + nb) * LD + ll;
      op[0]      = acc[i4][j2].x + b4.x;
      op[LD]     = acc[i4][j2].y + b4.y;
      op[2 * LD] = acc[i4][j2].z + b4.z;
      op[3 * LD] = acc[i4][j2].w + b4.w;
    }
  }
}

extern "C" void kernel_launch(void* const* d_in, const int* in_sizes, int n_in,
                              void* d_out, int out_size, void* d_ws, size_t ws_size,
                              hipStream_t stream) {
  const float* x = (const float*)d_in[0];
  const float* wgt = (const float*)d_in[1];
  const float* bias = (const float*)d_in[2];
  float* out = (float*)d_out;

  float* xpad = (float*)d_ws;                         // 30,408,704 B
  __hip_bfloat16* wqT = (__hip_bfloat16*)((char*)d_ws + 30408704);  // 1,179,648 B

  pad_kernel<<<8 * CD, 256, 0, stream>>>(x, xpad);
  quant_w_kernel<<<576, 256, 0, stream>>>(wgt, wqT);
  fused_gemm_kernel<<<392, 512, 0, stream>>>(xpad, wqT, bias, out);
}

// Round 10
// 102.958 us; speedup vs baseline: 1.0239x; 1.0239x over previous
//
#include <hip/hip_runtime.h>
#include <hip/hip_bf16.h>
#include <stdint.h>

// Problem constants
#define KD 2304    // K = C*3*3
#define LD 3136    // L = 56*56
#define ND 256     // output channels
#define MD 25088   // B*L
#define CD 256     // input channels
#define PITCH 64   // padded row pitch (floats)
#define PROWS 58
#define PLANE (PROWS * PITCH)

typedef __bf16 bf16x8 __attribute__((ext_vector_type(8)));
typedef float f32x4 __attribute__((ext_vector_type(4)));
typedef float f32x4u __attribute__((ext_vector_type(4), aligned(4)));

__device__ __forceinline__ void gload_lds16(const void* g, void* l) {
  __builtin_amdgcn_global_load_lds(
      (const __attribute__((address_space(1))) unsigned int*)g,
      (__attribute__((address_space(3))) unsigned int*)l, 16, 0, 0);
}

// ---------------- Phase -1: zero-pad x into [B*C][58][PITCH=64] ----------------
__global__ __launch_bounds__(256) void pad_kernel(
    const float* __restrict__ x, float* __restrict__ xpad) {
  const int plane = blockIdx.x;
  const float* src = x + (size_t)plane * LD;
  float* dst = xpad + (size_t)plane * PLANE;
  const int cc4 = (threadIdx.x & 15) * 4;
  const int r0 = threadIdx.x >> 4;
#pragma unroll
  for (int p = 0; p < 4; ++p) {
    const int r = r0 + p * 16;
    if (r >= PROWS) continue;
    f32x4 o = {0.f, 0.f, 0.f, 0.f};
    if (r >= 1 && r <= 56) {
      const float* srow = src + (r - 1) * 56;
      if (cc4 == 0) {
        f32x4u v = *(const f32x4u*)(srow);
        o[1] = v[0]; o[2] = v[1]; o[3] = v[2];
      } else if (cc4 <= 52) {
        o = *(const f32x4u*)(srow + cc4 - 1);
      } else if (cc4 == 56) {
        f32x4u v = *(const f32x4u*)(srow + 52);
        o[0] = v[3];
      }
    }
    *(f32x4*)(dst + r * PITCH + cc4) = o;
  }
}

// ---------------- Phase 0: weight fake-quant -> wqT [N][K] bf16 ----------------
__global__ __launch_bounds__(256) void quant_w_kernel(
    const float* __restrict__ w, __hip_bfloat16* __restrict__ wqT) {
  const int gk = blockIdx.x % 72;
  const int gn = blockIdx.x / 72;
  const int n = gn * 32 + (threadIdx.x >> 3);
  const int k = gk * 32 + (threadIdx.x & 7) * 4;
  const float4 v = *(const float4*)(w + (size_t)n * KD + k);
  float a = fmaxf(fmaxf(fabsf(v.x), fabsf(v.y)), fmaxf(fabsf(v.z), fabsf(v.w)));
#pragma unroll
  for (int m = 1; m <= 32; m <<= 1) a = fmaxf(a, __shfl_xor(a, m, 64));
  __shared__ float red[4];
  if ((threadIdx.x & 63) == 0) red[threadIdx.x >> 6] = a;
  __syncthreads();
  const float mx = fmaxf(fmaxf(red[0], red[1]), fmaxf(red[2], red[3]));
  const float r63 = (mx == 0.f) ? 0.f : 63.f / mx;
  const float scale = mx * (1.f / 63.f);
  ushort4 o;
  o.x = __builtin_bit_cast(unsigned short, __float2bfloat16(rintf(v.x * r63) * scale));
  o.y = __builtin_bit_cast(unsigned short, __float2bfloat16(rintf(v.y * r63) * scale));
  o.z = __builtin_bit_cast(unsigned short, __float2bfloat16(rintf(v.z * r63) * scale));
  o.w = __builtin_bit_cast(unsigned short, __float2bfloat16(rintf(v.w * r63) * scale));
  *(ushort4*)((unsigned short*)wqT + (size_t)n * KD + k) = o;
}

// ---- phase-exact window load for one 32-k granule ----
template <int KP0>
__device__ __forceinline__ void qloadT(const float* __restrict__ pb, int p0, int c0,
                                       f32x4u (&win)[5][3]) {
  constexpr int NCH = (KP0 + 31) / 9 + 1;   // 4 or 5 channels
#pragma unroll
  for (int dc = 0; dc < 5; ++dc) {
    if (dc >= NCH) continue;
    const int tlo = (dc == 0) ? KP0 : 0;
    const int thi = (dc == NCH - 1) ? (KP0 + 31 - 9 * (NCH - 1)) : 8;
    const int cdc = (c0 + dc > 255) ? 255 : c0 + dc;   // clamp for tail
    const float* cp = pb + p0 + cdc * PLANE;
#pragma unroll
    for (int di = 0; di < 3; ++di) {
      if (di >= tlo / 3 && di <= thi / 3)
        win[dc][di] = *(const f32x4u*)(cp + di * PITCH);
    }
  }
}

// ---- finish quant: tree-max, rcp, quant, cvt_pk, swizzled As write ----
// As rows 128B (64 k, 8 x 16B units); unit u of row r holds logical u^(r&7).
template <int KP0>
__device__ __forceinline__ void qfinishT(const f32x4u (&win)[5][3],
                                         char* __restrict__ as_base,
                                         int lane, unsigned cbase) {
  float v[32];
#pragma unroll
  for (int t = 0; t < 32; ++t) {
    const int idx = KP0 + t;
    v[t] = win[idx / 9][(idx % 9) / 3][(idx % 9) % 3];
  }
  float m16[16];
#pragma unroll
  for (int t = 0; t < 16; ++t)
    m16[t] = fmaxf(__builtin_fabsf(v[2 * t]), __builtin_fabsf(v[2 * t + 1]));
#pragma unroll
  for (int t = 0; t < 8; ++t) m16[t] = fmaxf(m16[t], m16[t + 8]);
#pragma unroll
  for (int t = 0; t < 4; ++t) m16[t] = fmaxf(m16[t], m16[t + 4]);
  const float mx = fmaxf(fmaxf(m16[0], m16[1]), fmaxf(m16[2], m16[3]));
  float r63 = 63.f * __builtin_amdgcn_rcpf(mx);
  r63 = (mx == 0.f) ? 0.f : r63;
  const float scale = mx * (1.f / 63.f);
  unsigned pk[16];
#pragma unroll
  for (int t = 0; t < 16; ++t) {
    const float a = rintf(v[2 * t] * r63) * scale;
    const float b = rintf(v[2 * t + 1] * r63) * scale;
    unsigned d;
    asm("v_cvt_pk_bf16_f32 %0, %1, %2" : "=v"(d) : "v"(a), "v"(b));
    pk[t] = d;
  }
  char* row = as_base + lane * 128;
  const unsigned swz = (unsigned)((lane & 7) << 4);
#pragma unroll
  for (int s = 0; s < 4; ++s) {
    uint4 o = {pk[4 * s], pk[4 * s + 1], pk[4 * s + 2], pk[4 * s + 3]};
    *(uint4*)(row + ((cbase + (unsigned)(s * 16)) ^ swz)) = o;
  }
}

#define SW_FIN(PH, DST, CB)                                                   \
  switch (PH) {                                                               \
    case 0: qfinishT<0>(win, DST, lane, CB); break;                           \
    case 1: qfinishT<1>(win, DST, lane, CB); break;                           \
    case 2: qfinishT<2>(win, DST, lane, CB); break;                           \
    case 3: qfinishT<3>(win, DST, lane, CB); break;                           \
    case 4: qfinishT<4>(win, DST, lane, CB); break;                           \
    case 5: qfinishT<5>(win, DST, lane, CB); break;                           \
    case 6: qfinishT<6>(win, DST, lane, CB); break;                           \
    case 7: qfinishT<7>(win, DST, lane, CB); break;                           \
    default: qfinishT<8>(win, DST, lane, CB); break;                          \
  }

#define SW_LOAD(PH, C0)                                                       \
  switch (PH) {                                                               \
    case 0: qloadT<0>(pb, p0, C0, win); break;                                \
    case 1: qloadT<1>(pb, p0, C0, win); break;                                \
    case 2: qloadT<2>(pb, p0, C0, win); break;                                \
    case 3: qloadT<3>(pb, p0, C0, win); break;                                \
    case 4: qloadT<4>(pb, p0, C0, win); break;                                \
    case 5: qloadT<5>(pb, p0, C0, win); break;                                \
    case 6: qloadT<6>(pb, p0, C0, win); break;                                \
    case 7: qloadT<7>(pb, p0, C0, win); break;                                \
    default: qloadT<8>(pb, p0, C0, win); break;                               \
  }

// ---- stage 256x64 wqT tile (32KB) via global_load_lds, pre-swizzled source ----
// 4 x 1KB chunks per wave (8 waves). vmcnt contribution: exactly 4 per wave.
__device__ __forceinline__ void stage_ns(const unsigned short* __restrict__ wsrc,
                                         int k0, int lane, int w,
                                         char* __restrict__ Ns) {
#pragma unroll
  for (int sg = 0; sg < 4; ++sg) {
    const int c = w * 4 + sg;              // 0..31, 1KB chunk = 8 rows x 128B
    const int row = c * 8 + (lane >> 3);
    const int u = (lane & 7) ^ (row & 7);
    gload_lds16(wsrc + (size_t)row * KD + k0 + u * 8, Ns + c * 1024 + lane * 16);
  }
}

// ---- MFMA: 8 waves, wave tile 64n x 32m, BK=64 (2 k-slices) ----
__device__ __forceinline__ void mfma_phase(const char* __restrict__ AsC,
                                           const char* __restrict__ Ns,
                                           f32x4 (&acc)[4][2], int w, int lq, int hv) {
  const int wn = w & 3, wm = w >> 2;
#pragma unroll
  for (int kk = 0; kk < 2; ++kk) {
    bf16x8 af[4], bf[2];
#pragma unroll
    for (int i = 0; i < 4; ++i) {
      const unsigned rn = (unsigned)(wn * 64 + i * 16 + lq);
      const unsigned u = (unsigned)((kk * 4 + hv) ^ (rn & 7));
      af[i] = *(const bf16x8*)(Ns + rn * 128u + u * 16u);
    }
#pragma unroll
    for (int j = 0; j < 2; ++j) {
      const unsigned rm = (unsigned)(wm * 32 + j * 16 + lq);
      const unsigned u = (unsigned)((kk * 4 + hv) ^ (rm & 7));
      bf[j] = *(const bf16x8*)(AsC + rm * 128u + u * 16u);
    }
#pragma unroll
    for (int i = 0; i < 4; ++i)
#pragma unroll
      for (int j = 0; j < 2; ++j)
        acc[i][j] = __builtin_amdgcn_mfma_f32_16x16x32_bf16(
            af[i], bf[j], acc[i][j], 0, 0, 0);
  }
}

// ---------------- Fused: ring-3 pipeline, ONE barrier per step ----------------
// 512 thr (8 waves), BM=64, BN=256 (quant-once), BK=64, 36 steps.
// LDS = As ring-3 (24K) + Ns ring-3 (96K) = 120K, 1 block/CU, 2 waves/SIMD.
// Step R: stage(R+1)->Ns[(R+1)%3] (4 async gload_lds/wave) | cadence wave
// qfinish->As[(R+1)%3] | BAR{vmcnt(4),lgkm(0)} | MFMA(As[R%3],Ns[R%3]) |
// cadence wave qload win for step R+5. Ring-3 + ahead-1 makes the single
// barrier race-free: slot (R+1)%3 was last read by MFMA(R-2), finished
// before BAR(R-1), and the writer runs after BAR(R-1).
__global__ __launch_bounds__(512, 2) void fused_gemm_kernel(
    const float* __restrict__ xpad, const __hip_bfloat16* __restrict__ wqT,
    const float* __restrict__ bias, float* __restrict__ out) {
  extern __shared__ char smem[];
  char* As = smem;                 // 3 x 8KB ring
  char* Ns = smem + 3 * 8192;      // 3 x 32KB ring
  const int tid = threadIdx.x;
  const int lane = tid & 63;
  const int w = __builtin_amdgcn_readfirstlane(tid >> 6);   // 0..7

  const int bid = blockIdx.x;                    // 0..391
  const int mt = (bid & 7) * 49 + (bid >> 3);    // XCD swizzle: image d -> XCD d
  const int m0 = mt * 64;

  const int b = m0 / LD;                         // uniform (3136 % 64 == 0)
  const int l = m0 - b * LD + lane;
  const int i = l / 56;
  const int j = l - i * 56;
  const float* pb = xpad + (size_t)b * CD * PLANE;
  const int p0 = i * PITCH + j;
  const unsigned short* wsrc = (const unsigned short*)wqT;

  const int slot = w & 1;                        // 32-k slot within BK=64
  const int g = w >> 1;                          // cadence group 0..3
  const unsigned cb = (unsigned)(slot * 64);     // byte base within 128B As row
  const int lq = lane & 15, hv = lane >> 4;

  f32x4 acc[4][2] = {};
  f32x4u win[5][3];

  // ---- prologue ----
  // g=3 waves produce As[0] (for step 0): k = slot*32 -> phase 0 / 5.
  if (g == 3) {
    if (slot == 0) { qloadT<0>(pb, p0, 0, win); qfinishT<0>(win, As, lane, 0u); }
    else           { qloadT<5>(pb, p0, 3, win); qfinishT<5>(win, As, lane, 64u); }
  }
  // every wave pre-loads win for its first in-loop production:
  // g in {0,1,2}: produces at R=g for step g+1; g=3: produces at R=3 for step 4.
  int kq = ((g == 3) ? 4 : (g + 1)) * 64 + slot * 32;
  int phq = kq % 9;
  { const int c0_ = kq / 9; SW_LOAD(phq, c0_); }
  stage_ns(wsrc, 0, lane, w, Ns);                // Ns[0] for step 0
  asm volatile("s_waitcnt vmcnt(0) lgkmcnt(0)\n\ts_barrier" ::: "memory");
  __builtin_amdgcn_sched_barrier(0);

  for (int R = 0; R < 36; ++R) {
    // stage next tile (re-stage 35 on last iter keeps vmcnt constant uniform)
    const int Rs = (R < 35) ? (R + 1) : 35;
    stage_ns(wsrc, Rs * 64, lane, w, Ns + ((R + 1) % 3) * 32768);

    const bool cad = ((R & 3) == g);
    if (cad && R <= 34) {                        // produce As for step R+1
      char* dst = As + ((R + 1) % 3) * 8192;
      SW_FIN(phq, dst, cb);
    }

    // drain everything except the 4 newest (= stage(R+1)); publish ds_writes
    asm volatile("s_waitcnt vmcnt(4) lgkmcnt(0)\n\ts_barrier" ::: "memory");
    __builtin_amdgcn_sched_barrier(0);

    __builtin_amdgcn_s_setprio(1);
    mfma_phase(As + (R % 3) * 8192, Ns + (R % 3) * 32768, acc, w, lq, hv);
    __builtin_amdgcn_s_setprio(0);

    if (cad && R <= 30) {                        // prefetch win for step R+5
      kq += 256;
      phq += 4; if (phq >= 9) phq -= 9;
      const int c0_ = kq / 9;
      SW_LOAD(phq, c0_);
    }
  }

  // ---- Epilogue: D row = n = (w&3)*64 + i*16 + hv*4 + comp, col = m ----
#pragma unroll
  for (int i4 = 0; i4 < 4; ++i4) {
    const int nb = (w & 3) * 64 + i4 * 16 + hv * 4;
    const float4 b4 = *(const float4*)&bias[nb];
#pragma unroll
    for (int j2 = 0; j2 < 2; ++j2) {
      const int m = m0 + (w >> 2) * 32 + j2 * 16 + lq;
      const int ll = m - b * LD;
      float* op = out + ((size_t)b * ND + nb) * LD + ll;
      op[0]      = acc[i4][j2].x + b4.x;
      op[LD]     = acc[i4][j2].y + b4.y;
      op[2 * LD] = acc[i4][j2].z + b4.z;
      op[3 * LD] = acc[i4][j2].w + b4.w;
    }
  }
}

extern "C" void kernel_launch(void* const* d_in, const int* in_sizes, int n_in,
                              void* d_out, int out_size, void* d_ws, size_t ws_size,
                              hipStream_t stream) {
  const float* x = (const float*)d_in[0];
  const float* wgt = (const float*)d_in[1];
  const float* bias = (const float*)d_in[2];
  float* out = (float*)d_out;

  float* xpad = (float*)d_ws;                         // 30,408,704 B
  __hip_bfloat16* wqT = (__hip_bfloat16*)((char*)d_ws + 30408704);  // 1,179,648 B

  pad_kernel<<<8 * CD, 256, 0, stream>>>(x, xpad);
  quant_w_kernel<<<576, 256, 0, stream>>>(wgt, wqT);
  fused_gemm_kernel<<<392, 512, 3 * 8192 + 3 * 32768, stream>>>(xpad, wqT, bias, out);
}